// Round 6
// baseline (185.008 us; speedup 1.0000x reference)
//
#include <hip/hip_runtime.h>
#include <hip/hip_bf16.h>

// Problem constants (fixed by the reference): N_CLASS=200, N_MU=1024, D=512, K=512
constexpr int N_CLASS = 200;
constexpr int N_MU    = 1024;
constexpr int DIM     = 512;
constexpr int KIN     = 512;
constexpr int NCAND   = N_MU + KIN;      // 1536 candidates
constexpr int SORTN   = 2048;            // next pow2
constexpr int RPW     = 8;               // rows per wave (output kernels)

// clang ext-vector (NOT HIP_vector_type) so __builtin_nontemporal_* accepts it
typedef float f4 __attribute__((ext_vector_type(4)));

// ---------------------------------------------------------------------------
// Kernel 1: per-class stable top-1024 selection via bitonic sort.
// Key = (~sortable(score) << 32) | index  -> ascending sort == descending
// score with lower-index-first tie break (matches XLA top_k stability).
// Also scatters the inverse map inv_q[c][src] = dst for surviving QUEUE
// candidates (pass1 consumes it in ascending-source order).
// ---------------------------------------------------------------------------
__global__ __launch_bounds__(1024) void sort_kernel(
    const float* __restrict__ q_sc,    // [N_CLASS, N_MU]
    const float* __restrict__ inp_sc,  // [KIN, N_CLASS]
    const int*   __restrict__ cls_idx, // [n_idx]
    int*         __restrict__ ws_idx,  // [N_CLASS, N_MU]
    float*       __restrict__ ws_sc,   // [N_CLASS, N_MU]
    int*         __restrict__ inv_q,   // [N_CLASS, N_MU], pre-set to -1
    int*         __restrict__ flags)   // [N_CLASS]
{
    __shared__ unsigned long long keys[SORTN];
    const int e = blockIdx.x;
    const int c = cls_idx[e];
    const int t = threadIdx.x;

    for (int i = t; i < SORTN; i += 1024) {
        unsigned long long key;
        if (i < NCAND) {
            float f = (i < N_MU) ? q_sc[(size_t)c * N_MU + i]
                                 : inp_sc[(size_t)(i - N_MU) * N_CLASS + c];
            unsigned u = __float_as_uint(f);
            unsigned s = (u & 0x80000000u) ? ~u : (u | 0x80000000u);
            unsigned inv = ~s; // descending
            key = ((unsigned long long)inv << 32) | (unsigned)i;
        } else {
            key = 0xFFFFFFFFFFFFFFFFull; // pad sorts last
        }
        keys[i] = key;
    }
    __syncthreads();

    for (int k = 2; k <= SORTN; k <<= 1) {
        for (int j = k >> 1; j > 0; j >>= 1) {
            const int i = ((t & ~(j - 1)) << 1) | (t & (j - 1));
            const int p = i | j;
            const bool asc = ((i & k) == 0);
            unsigned long long a = keys[i], b = keys[p];
            const bool sw = asc ? (a > b) : (a < b);
            if (sw) { keys[i] = b; keys[p] = a; }
            __syncthreads();
        }
    }

    {
        unsigned long long key = keys[t];
        const int idx = (int)(key & 0xFFFFFFFFu);
        unsigned s = ~((unsigned)(key >> 32));
        unsigned u = (s & 0x80000000u) ? (s & 0x7FFFFFFFu) : ~s;
        ws_idx[((size_t)c << 10) + t] = idx;
        ws_sc [((size_t)c << 10) + t] = __uint_as_float(u);
        if (idx < N_MU) inv_q[((size_t)c << 10) + idx] = t;   // inverse map
    }
    if (t == 0) flags[c] = 1;
}

// ---------------------------------------------------------------------------
// Register-shuffle row store (validated in R5, absmax=0): source row P
// (512 aligned floats) + score S -> out row at float offset O = drow*513,
// head-misaligned by c0 = (-O) mod 4. Two aligned f4 loads per lane,
// cross-lane shift via __shfl_down, aligned nontemporal f4 stores +
// <=5 scalar head/tail floats. No LDS, no __syncthreads.
// ---------------------------------------------------------------------------
__device__ __forceinline__ void store_row(
    const float* __restrict__ P, float S, size_t drow,
    float* __restrict__ out, int lane)
{
    const size_t O = drow * (size_t)(DIM + 1);
    const int c0 = (int)((4 - (O & 3)) & 3);
    const int n_full = (513 - c0) >> 2;

    const f4* Pv = (const f4*)P;
    const f4 v0 = Pv[lane];
    const f4 v1 = Pv[64 + lane];

    f4 o0, o1;
    if (c0 == 0) {
        o0 = v0; o1 = v1;
    } else {
        f4 nb0, nb1;
#pragma unroll
        for (int i = 0; i < 4; ++i) {
            const float d0 = __shfl_down(v0[i], 1);
            const float b1 = __shfl(v1[i], 0);
            nb0[i] = (lane == 63) ? b1 : d0;
            const float d1 = __shfl_down(v1[i], 1);
            nb1[i] = (lane == 63) ? S : d1;
        }
        if (c0 == 1) {
            o0 = f4{v0.y, v0.z, v0.w, nb0.x};
            o1 = f4{v1.y, v1.z, v1.w, nb1.x};
        } else if (c0 == 2) {
            o0 = f4{v0.z, v0.w, nb0.x, nb0.y};
            o1 = f4{v1.z, v1.w, nb1.x, nb1.y};
        } else {
            o0 = f4{v0.w, nb0.x, nb0.y, nb0.z};
            o1 = f4{v1.w, nb1.x, nb1.y, nb1.z};
        }
    }
    f4* outv = (f4*)(out + O + c0);
    __builtin_nontemporal_store(o0, outv + lane);
    if (lane < n_full - 64)
        __builtin_nontemporal_store(o1, outv + 64 + lane);

    if (lane < c0) out[O + lane] = P[lane];
    const int tail  = c0 + 4 * n_full;
    const int ntail = 513 - tail;
    if (lane >= 8 && lane < 8 + ntail) {
        const int q = tail + (lane - 8);
        out[O + q] = (q < 512) ? P[q] : S;
    }
}

// ---------------------------------------------------------------------------
// Pass 1: queue-sourced rows, iterated in ASCENDING SOURCE order so q_mu
// reads are sequential-with-gaps. Wave per 8 source rows; non-survivors
// skip before touching row data. Writes scatter to inv_q destinations.
// Passthrough classes (flags==0) copy identity.
// ---------------------------------------------------------------------------
__global__ __launch_bounds__(256) void pass1_kernel(
    const float* __restrict__ q_mu,   // [N_CLASS, N_MU, DIM]
    const float* __restrict__ q_sc,   // [N_CLASS, N_MU]
    const int*   __restrict__ inv_q,  // [N_CLASS, N_MU]
    const float* __restrict__ ws_sc,  // [N_CLASS, N_MU]
    const int*   __restrict__ flags,  // [N_CLASS]
    float*       __restrict__ out)    // [N_CLASS, N_MU, DIM+1]
{
    const int lane = threadIdx.x & 63;
    const size_t wave = (size_t)blockIdx.x * 4 + (threadIdx.x >> 6);
    const size_t src0 = wave * RPW;

#pragma unroll 2
    for (int rr = 0; rr < RPW; ++rr) {
        const size_t srow = src0 + rr;          // ascending source row
        const int c = (int)(srow >> 10);
        int d; float S;
        if (flags[c] != 0) {
            d = inv_q[srow];
            if (d < 0) continue;                // dropped: no row data touched
            S = ws_sc[((size_t)c << 10) + d];
        } else {
            d = (int)(srow & 1023);             // identity passthrough
            S = q_sc[srow];
        }
        store_row(q_mu + srow * DIM, S, ((size_t)c << 10) + d, out, lane);
    }
}

// ---------------------------------------------------------------------------
// Pass 2: input-sourced rows only. inp_mu is 1 MB -> L2/L3-resident for the
// whole pass (no per-class re-fetch). Wave per 8 output rows, skipping
// queue-sourced ones.
// ---------------------------------------------------------------------------
__global__ __launch_bounds__(256) void pass2_kernel(
    const float* __restrict__ inp_mu, // [KIN, DIM]
    const int*   __restrict__ ws_idx, // [N_CLASS, N_MU]
    const float* __restrict__ ws_sc,  // [N_CLASS, N_MU]
    const int*   __restrict__ flags,  // [N_CLASS]
    float*       __restrict__ out)    // [N_CLASS, N_MU, DIM+1]
{
    const int lane = threadIdx.x & 63;
    const size_t wave = (size_t)blockIdx.x * 4 + (threadIdx.x >> 6);
    const size_t row0 = wave * RPW;

#pragma unroll 2
    for (int rr = 0; rr < RPW; ++rr) {
        const size_t row = row0 + rr;
        const int c = (int)(row >> 10);
        if (flags[c] == 0) continue;
        const int idx = ws_idx[row];
        if (idx < N_MU) continue;               // queue-sourced: pass1's job
        store_row(inp_mu + (size_t)(idx - N_MU) * DIM, ws_sc[row], row, out, lane);
    }
}

extern "C" void kernel_launch(void* const* d_in, const int* in_sizes, int n_in,
                              void* d_out, int out_size, void* d_ws, size_t ws_size,
                              hipStream_t stream) {
    const float* q_mu    = (const float*)d_in[0];
    const float* q_sc    = (const float*)d_in[1];
    const float* inp_mu  = (const float*)d_in[2];
    const float* inp_sc  = (const float*)d_in[3];
    const int*   cls_idx = (const int*)d_in[4];
    float* out = (float*)d_out;
    const int n_idx = in_sizes[4];

    // workspace: ws_idx [200*1024 int] | ws_sc [200*1024 f32] | inv_q [200*1024 int] | flags [200 int]
    constexpr size_t NQ = (size_t)N_CLASS * N_MU;
    int*   ws_idx = (int*)d_ws;
    float* ws_sc  = (float*)((char*)d_ws + NQ * 4);
    int*   inv_q  = (int*)((char*)d_ws + NQ * 8);
    int*   flags  = (int*)((char*)d_ws + NQ * 12);

    (void)hipMemsetAsync(inv_q, 0xFF, NQ * sizeof(int), stream);   // -1
    (void)hipMemsetAsync(flags, 0, N_CLASS * sizeof(int), stream);
    sort_kernel<<<n_idx, 1024, 0, stream>>>(
        q_sc, inp_sc, cls_idx, ws_idx, ws_sc, inv_q, flags);

    const int total_rows = N_CLASS * N_MU;       // 204800
    const int blocks = total_rows / (4 * RPW);   // 6400
    pass1_kernel<<<blocks, 256, 0, stream>>>(q_mu, q_sc, inv_q, ws_sc, flags, out);
    pass2_kernel<<<blocks, 256, 0, stream>>>(inp_mu, ws_idx, ws_sc, flags, out);
}

// Round 7
// 148.306 us; speedup vs baseline: 1.2475x; 1.2475x over previous
//
#include <hip/hip_runtime.h>
#include <hip/hip_bf16.h>

// Problem constants (fixed by the reference): N_CLASS=200, N_MU=1024, D=512, K=512
constexpr int N_CLASS = 200;
constexpr int N_MU    = 1024;
constexpr int DIM     = 512;
constexpr int KIN     = 512;
constexpr int NCAND   = N_MU + KIN;      // 1536 candidates
constexpr int SORTN   = 2048;            // next pow2
constexpr int RPB     = 16;              // rows per output block
constexpr int TPB     = 512;             // threads per output block

// clang ext-vector (NOT HIP_vector_type) so __builtin_nontemporal_* accepts it
typedef float f4 __attribute__((ext_vector_type(4)));

// ---------------------------------------------------------------------------
// Kernel 1: per-class stable top-1024 selection via bitonic sort.
// Key = (~sortable(score) << 32) | index  -> ascending sort == descending
// score with lower-index-first tie break (matches XLA top_k stability).
// Workspace indexed by CLASS id c. Sets flags[c]=1.
// ---------------------------------------------------------------------------
__global__ __launch_bounds__(1024) void sort_kernel(
    const float* __restrict__ q_sc,    // [N_CLASS, N_MU]
    const float* __restrict__ inp_sc,  // [KIN, N_CLASS]
    const int*   __restrict__ cls_idx, // [n_idx]
    int*         __restrict__ ws_idx,  // [N_CLASS, N_MU]
    float*       __restrict__ ws_sc,   // [N_CLASS, N_MU]
    int*         __restrict__ flags)   // [N_CLASS]
{
    __shared__ unsigned long long keys[SORTN];
    const int e = blockIdx.x;
    const int c = cls_idx[e];
    const int t = threadIdx.x;

    for (int i = t; i < SORTN; i += 1024) {
        unsigned long long key;
        if (i < NCAND) {
            float f = (i < N_MU) ? q_sc[(size_t)c * N_MU + i]
                                 : inp_sc[(size_t)(i - N_MU) * N_CLASS + c];
            unsigned u = __float_as_uint(f);
            unsigned s = (u & 0x80000000u) ? ~u : (u | 0x80000000u);
            unsigned inv = ~s; // descending
            key = ((unsigned long long)inv << 32) | (unsigned)i;
        } else {
            key = 0xFFFFFFFFFFFFFFFFull; // pad sorts last
        }
        keys[i] = key;
    }
    __syncthreads();

    for (int k = 2; k <= SORTN; k <<= 1) {
        for (int j = k >> 1; j > 0; j >>= 1) {
            const int i = ((t & ~(j - 1)) << 1) | (t & (j - 1));
            const int p = i | j;
            const bool asc = ((i & k) == 0);
            unsigned long long a = keys[i], b = keys[p];
            const bool sw = asc ? (a > b) : (a < b);
            if (sw) { keys[i] = b; keys[p] = a; }
            __syncthreads();
        }
    }

    {
        unsigned long long key = keys[t];
        const int idx = (int)(key & 0xFFFFFFFFu);
        unsigned s = ~((unsigned)(key >> 32));
        unsigned u = (s & 0x80000000u) ? (s & 0x7FFFFFFFu) : ~s;
        ws_idx[((size_t)c << 10) + t] = idx;
        ws_sc [((size_t)c << 10) + t] = __uint_as_float(u);
    }
    if (t == 0) flags[c] = 1;
}

// ---------------------------------------------------------------------------
// Kernel 2 (fused gather+fill): one 512-thread block per (class, 16-row
// group). Structure = R3's winner (gathered f4 reads, dense contiguous f4
// nontemporal writes), scaled 2x:
//   - 16 rows -> 32832 B contiguous write run per block, 12800 blocks
//   - LDS 32.8 KB -> 4 blocks/CU x 512 thr = full 2048-thread occupancy
//   - per-row source pointer + nt-flag resolved ONCE into an LDS table
//   - staging: f4 loads (128 lanes per row, fully coalesced 2 KB/row);
//     NT for read-once q_mu rows, plain for L2-resident inp_mu rows
//     (branch is wave-uniform: each wave covers half a row)
// ---------------------------------------------------------------------------
__global__ __launch_bounds__(TPB) void out_kernel(
    const float* __restrict__ q_mu,   // [N_CLASS, N_MU, DIM]
    const float* __restrict__ q_sc,   // [N_CLASS, N_MU]
    const float* __restrict__ inp_mu, // [KIN, DIM]
    const int*   __restrict__ ws_idx, // [N_CLASS, N_MU]
    const float* __restrict__ ws_sc,  // [N_CLASS, N_MU]
    const int*   __restrict__ flags,  // [N_CLASS]
    float*       __restrict__ out)    // [N_CLASS, N_MU, DIM+1]
{
    __shared__ __align__(16) float buf[RPB * (DIM + 1)]; // 8208 floats
    __shared__ const f4* selp[RPB];                      // per-row source ptr
    __shared__ int       snt[RPB];                       // 1 = nontemporal load
    __shared__ float     ssc[RPB];                       // per-row score

    const int b  = blockIdx.x;
    const int c  = b >> 6;          // 64 groups per class
    const int g  = b & 63;
    const int j0 = g * RPB;
    const int t  = threadIdx.x;
    const size_t rowbase = ((size_t)c << 10) + j0;

    if (t < RPB) {
        if (flags[c] != 0) {
            const int idx = ws_idx[rowbase + t];
            if (idx < N_MU) {
                selp[t] = (const f4*)(q_mu + (((size_t)c << 10) + idx) * DIM);
                snt[t] = 1;                               // read-once gather
            } else {
                selp[t] = (const f4*)(inp_mu + (size_t)(idx - N_MU) * DIM);
                snt[t] = 0;                               // keep in L2
            }
            ssc[t] = ws_sc[rowbase + t];
        } else {
            selp[t] = (const f4*)(q_mu + (rowbase + t) * DIM);
            snt[t] = 1;
            ssc[t] = q_sc[rowbase + t];
        }
    }
    __syncthreads();

    // stage 16 rows x 128 f4: 4 iterations, 4 rows per iteration,
    // 128 lanes (2 waves) per row -> wave-uniform snt branch
#pragma unroll
    for (int j = 0; j < 4; ++j) {
        const int fq = t + TPB * j;   // 0..2047
        const int r  = fq >> 7;       // row 0..15
        const int q  = fq & 127;      // f4 within row
        const f4* src = selp[r] + q;
        f4 v;
        if (snt[r]) v = __builtin_nontemporal_load(src);
        else        v = *src;
        float* d = buf + r * (DIM + 1) + q * 4;
        d[0] = v.x; d[1] = v.y; d[2] = v.z; d[3] = v.w;
    }
    if (t < RPB) buf[t * (DIM + 1) + DIM] = ssc[t];
    __syncthreads();

    // stream the 32832-B region out as 2052 f4 nontemporal stores
    f4* dst = (f4*)(out + rowbase * (DIM + 1));
#pragma unroll
    for (int j = 0; j < 5; ++j) {
        const int l = t + TPB * j;
        if (l < RPB * (DIM + 1) / 4) {
            __builtin_nontemporal_store(*(const f4*)(buf + l * 4), dst + l);
        }
    }
}

extern "C" void kernel_launch(void* const* d_in, const int* in_sizes, int n_in,
                              void* d_out, int out_size, void* d_ws, size_t ws_size,
                              hipStream_t stream) {
    const float* q_mu    = (const float*)d_in[0];
    const float* q_sc    = (const float*)d_in[1];
    const float* inp_mu  = (const float*)d_in[2];
    const float* inp_sc  = (const float*)d_in[3];
    const int*   cls_idx = (const int*)d_in[4];
    float* out = (float*)d_out;
    const int n_idx = in_sizes[4];

    // workspace: ws_idx [200*1024 int] | ws_sc [200*1024 f32] | flags [200 int]
    constexpr size_t NQ = (size_t)N_CLASS * N_MU;
    int*   ws_idx = (int*)d_ws;
    float* ws_sc  = (float*)((char*)d_ws + NQ * 4);
    int*   flags  = (int*)((char*)d_ws + NQ * 8);

    (void)hipMemsetAsync(flags, 0, N_CLASS * sizeof(int), stream);
    sort_kernel<<<n_idx, 1024, 0, stream>>>(
        q_sc, inp_sc, cls_idx, ws_idx, ws_sc, flags);
    out_kernel<<<N_CLASS * (N_MU / RPB), TPB, 0, stream>>>(
        q_mu, q_sc, inp_mu, ws_idx, ws_sc, flags, out);
}

// Round 8
// 143.111 us; speedup vs baseline: 1.2928x; 1.0363x over previous
//
#include <hip/hip_runtime.h>
#include <hip/hip_bf16.h>

// Problem constants (fixed by the reference): N_CLASS=200, N_MU=1024, D=512, K=512
constexpr int N_CLASS = 200;
constexpr int N_MU    = 1024;
constexpr int DIM     = 512;
constexpr int KIN     = 512;
constexpr int NCAND   = N_MU + KIN;      // 1536 candidates
constexpr int SORTN   = 2048;            // next pow2
constexpr int RPB     = 16;              // rows per output block
constexpr int TPB     = 512;             // threads per output block

typedef float f4 __attribute__((ext_vector_type(4)));
typedef unsigned long long u64;

// ---------------------------------------------------------------------------
// Kernel 1: per-class stable top-1024 via hybrid shfl/LDS bitonic sort.
// Element layout: i = wave*128 + lane*2 + slot  ->
//   j==1   : in-thread compare-exchange
//   j=2..64: __shfl_xor(j>>1) within wave (no barrier)
//   j>=128 : LDS pair stages (barriered) — 14 barriers total vs 66.
// Key = (~sortable(score) << 32) | index : ascending == descending score,
// lower-index-first on ties (matches XLA top_k stability).
// ---------------------------------------------------------------------------
__global__ __launch_bounds__(1024) void sort_kernel(
    const float* __restrict__ q_sc,    // [N_CLASS, N_MU]
    const float* __restrict__ inp_sc,  // [KIN, N_CLASS]
    const int*   __restrict__ cls_idx, // [n_idx]
    int*         __restrict__ ws_idx,  // [N_CLASS, N_MU]
    float*       __restrict__ ws_sc,   // [N_CLASS, N_MU]
    int*         __restrict__ flags)   // [N_CLASS]
{
    __shared__ u64 keys[SORTN];
    const int c = cls_idx[blockIdx.x];
    const int t = threadIdx.x;
    const int lane = t & 63;
    const int w    = t >> 6;
    const int i0   = (w << 7) | (lane << 1);   // my slot-0 element index
    const int i1   = i0 | 1;

    auto make_key = [&](int i) -> u64 {
        if (i >= NCAND) return 0xFFFFFFFFFFFFFFFFull;
        float f = (i < N_MU) ? q_sc[(size_t)c * N_MU + i]
                             : inp_sc[(size_t)(i - N_MU) * N_CLASS + c];
        unsigned u = __float_as_uint(f);
        unsigned s = (u & 0x80000000u) ? ~u : (u | 0x80000000u);
        return ((u64)(~s) << 32) | (unsigned)i;
    };
    u64 e0 = make_key(i0);
    u64 e1 = make_key(i1);

    for (int k = 2; k <= SORTN; k <<= 1) {
        // --- cross-wave stages (j >= 128) through LDS ---
        if (k >= 256) {
            keys[i0] = e0; keys[i1] = e1;
            __syncthreads();
            for (int j = k >> 1; j >= 128; j >>= 1) {
                const int i = ((t & ~(j - 1)) << 1) | (t & (j - 1));
                const int p = i | j;
                const bool asc = ((i & k) == 0);
                u64 a = keys[i], b = keys[p];
                const bool sw = asc ? (a > b) : (a < b);
                if (sw) { keys[i] = b; keys[p] = a; }
                __syncthreads();
            }
            e0 = keys[i0]; e1 = keys[i1];
        }
        // --- intra-wave stages j = min(k/2,64) .. 2 via shfl_xor ---
        const bool asc = ((i0 & k) == 0);      // same for both slots (k >= 2)
        for (int j = (k >> 1) < 64 ? (k >> 1) : 64; j >= 2; j >>= 1) {
            const u64 o0 = __shfl_xor(e0, j >> 1);
            const u64 o1 = __shfl_xor(e1, j >> 1);
            const bool low = ((i0 & j) == 0);  // same for both slots (j >= 2)
            const bool takeMin = (low == asc);
            e0 = takeMin ? (e0 < o0 ? e0 : o0) : (e0 > o0 ? e0 : o0);
            e1 = takeMin ? (e1 < o1 ? e1 : o1) : (e1 > o1 ? e1 : o1);
        }
        // --- j == 1 in-thread ---
        {
            const u64 lo = e0 < e1 ? e0 : e1;
            const u64 hi = e0 < e1 ? e1 : e0;
            e0 = asc ? lo : hi;
            e1 = asc ? hi : lo;
        }
    }

    // elements 0..1023 (waves 0..7) are the stable top-1024
    if (w < 8) {
        auto emit = [&](u64 key, int slot) {
            const int idx = (int)(key & 0xFFFFFFFFu);
            unsigned s = ~((unsigned)(key >> 32));
            unsigned u = (s & 0x80000000u) ? (s & 0x7FFFFFFFu) : ~s;
            ws_idx[((size_t)c << 10) + slot] = idx;
            ws_sc [((size_t)c << 10) + slot] = __uint_as_float(u);
        };
        emit(e0, i0);
        emit(e1, i1);
    }
    if (t == 0) flags[c] = 1;
}

// ---------------------------------------------------------------------------
// Kernel 2 (fused gather+fill, software-pipelined): one 512-thread block per
// (class, 16-row group). No resolve table/barrier — per-lane ws_idx loads
// broadcast from L1. Two-half pipeline:
//   A: stage rows 0-7 -> barrier
//   B: ISSUE row 8-15 global loads, then stream rows 0-7 stores (loads in
//      flight under the stores), ds_write rows 8-15 -> barrier
//   C: stream rows 8-15 stores
// All global traffic f4; NT on read-once q_mu and all out stores; plain
// loads keep 1 MB inp_mu L2-resident.
// ---------------------------------------------------------------------------
__global__ __launch_bounds__(TPB) void out_kernel(
    const float* __restrict__ q_mu,   // [N_CLASS, N_MU, DIM]
    const float* __restrict__ q_sc,   // [N_CLASS, N_MU]
    const float* __restrict__ inp_mu, // [KIN, DIM]
    const int*   __restrict__ ws_idx, // [N_CLASS, N_MU]
    const float* __restrict__ ws_sc,  // [N_CLASS, N_MU]
    const int*   __restrict__ flags,  // [N_CLASS]
    float*       __restrict__ out)    // [N_CLASS, N_MU, DIM+1]
{
    __shared__ __align__(16) float buf[RPB * (DIM + 1)]; // 8208 floats
    const int b  = blockIdx.x;
    const int c  = b >> 6;          // 64 groups per class
    const int g  = b & 63;
    const int j0 = g * RPB;
    const int t  = threadIdx.x;
    const size_t rowbase = ((size_t)c << 10) + j0;
    const bool upd = (flags[c] != 0);

    auto load_f4 = [&](int r, int q) -> f4 {
        if (upd) {
            const int idx = ws_idx[rowbase + r];
            if (idx < N_MU) {
                return __builtin_nontemporal_load(
                    (const f4*)(q_mu + (((size_t)c << 10) + idx) * DIM) + q);
            }
            return *((const f4*)(inp_mu + (size_t)(idx - N_MU) * DIM) + q);
        }
        return __builtin_nontemporal_load(
            (const f4*)(q_mu + (rowbase + r) * DIM) + q);
    };
    auto load_sc = [&](int r) -> float {
        return upd ? ws_sc[rowbase + r] : q_sc[rowbase + r];
    };
    f4* dst = (f4*)(out + rowbase * (size_t)(DIM + 1));

    // ---- phase A: stage rows 0-7 ----
    {
        f4 v[2];
#pragma unroll
        for (int j = 0; j < 2; ++j) {
            const int fq = t + TPB * j;       // 0..1023
            v[j] = load_f4(fq >> 7, fq & 127);
        }
        float s = (t < 8) ? load_sc(t) : 0.0f;
#pragma unroll
        for (int j = 0; j < 2; ++j) {
            const int fq = t + TPB * j;
            const int r = fq >> 7, q = fq & 127;
            float* d = buf + r * (DIM + 1) + q * 4;
            d[0] = v[j].x; d[1] = v[j].y; d[2] = v[j].z; d[3] = v[j].w;
        }
        if (t < 8) buf[t * (DIM + 1) + DIM] = s;
    }
    __syncthreads();

    // ---- phase B: issue rows 8-15 loads, store rows 0-7, write rows 8-15 ----
    {
        f4 v[2];
#pragma unroll
        for (int j = 0; j < 2; ++j) {
            const int fq = 1024 + t + TPB * j;  // 1024..2047
            v[j] = load_f4(fq >> 7, fq & 127);
        }
        float s = (t < 8) ? load_sc(8 + t) : 0.0f;

        // store region A: f4 slots [0, 1026) — floats [0, 4104) = rows 0-7
        __builtin_nontemporal_store(*(const f4*)(buf + t * 4),            dst + t);
        __builtin_nontemporal_store(*(const f4*)(buf + (TPB + t) * 4),    dst + TPB + t);
        if (t < 2)
            __builtin_nontemporal_store(*(const f4*)(buf + (1024 + t) * 4), dst + 1024 + t);

#pragma unroll
        for (int j = 0; j < 2; ++j) {
            const int fq = 1024 + t + TPB * j;
            const int r = fq >> 7, q = fq & 127;
            float* d = buf + r * (DIM + 1) + q * 4;
            d[0] = v[j].x; d[1] = v[j].y; d[2] = v[j].z; d[3] = v[j].w;
        }
        if (t < 8) buf[(8 + t) * (DIM + 1) + DIM] = s;
    }
    __syncthreads();

    // ---- phase C: store region B: f4 slots [1026, 2052) ----
    __builtin_nontemporal_store(*(const f4*)(buf + (1026 + t) * 4),       dst + 1026 + t);
    __builtin_nontemporal_store(*(const f4*)(buf + (1538 + t) * 4),       dst + 1538 + t);
    if (t < 2)
        __builtin_nontemporal_store(*(const f4*)(buf + (2050 + t) * 4),   dst + 2050 + t);
}

extern "C" void kernel_launch(void* const* d_in, const int* in_sizes, int n_in,
                              void* d_out, int out_size, void* d_ws, size_t ws_size,
                              hipStream_t stream) {
    const float* q_mu    = (const float*)d_in[0];
    const float* q_sc    = (const float*)d_in[1];
    const float* inp_mu  = (const float*)d_in[2];
    const float* inp_sc  = (const float*)d_in[3];
    const int*   cls_idx = (const int*)d_in[4];
    float* out = (float*)d_out;
    const int n_idx = in_sizes[4];

    // workspace: ws_idx [200*1024 int] | ws_sc [200*1024 f32] | flags [200 int]
    constexpr size_t NQ = (size_t)N_CLASS * N_MU;
    int*   ws_idx = (int*)d_ws;
    float* ws_sc  = (float*)((char*)d_ws + NQ * 4);
    int*   flags  = (int*)((char*)d_ws + NQ * 8);

    (void)hipMemsetAsync(flags, 0, N_CLASS * sizeof(int), stream);
    sort_kernel<<<n_idx, 1024, 0, stream>>>(
        q_sc, inp_sc, cls_idx, ws_idx, ws_sc, flags);
    out_kernel<<<N_CLASS * (N_MU / RPB), TPB, 0, stream>>>(
        q_mu, q_sc, inp_mu, ws_idx, ws_sc, flags, out);
}

// Round 9
// 138.473 us; speedup vs baseline: 1.3361x; 1.0335x over previous
//
#include <hip/hip_runtime.h>
#include <hip/hip_bf16.h>

// Problem constants (fixed by the reference): N_CLASS=200, N_MU=1024, D=512, K=512
constexpr int N_CLASS = 200;
constexpr int N_MU    = 1024;
constexpr int DIM     = 512;
constexpr int KIN     = 512;
constexpr int NCAND   = N_MU + KIN;      // 1536 candidates
constexpr int SORTN   = 2048;            // next pow2
constexpr int RPB     = 16;              // rows per output block
constexpr int TPB     = 512;             // threads per output block

typedef float f4 __attribute__((ext_vector_type(4)));
typedef unsigned long long u64;

// ---------------------------------------------------------------------------
// Kernel 1: grid = N_CLASS. Block e first determines whether class e is
// listed in cls_idx (replaces the flags memset dispatch; also dedups).
// If listed: stable top-1024 via hybrid shfl/LDS bitonic sort.
//   j==1   : in-thread compare-exchange
//   j=2..64: __shfl_xor within wave (no barrier)
//   j>=128 : LDS pair stages (14 barriers total vs 66)
// Key = (~sortable(score) << 32) | index : ascending == descending score,
// lower-index-first on ties (matches XLA top_k stability).
// ---------------------------------------------------------------------------
__global__ __launch_bounds__(1024) void sort_kernel(
    const float* __restrict__ q_sc,    // [N_CLASS, N_MU]
    const float* __restrict__ inp_sc,  // [KIN, N_CLASS]
    const int*   __restrict__ cls_idx, // [n_idx]
    int          n_idx,
    int*         __restrict__ ws_idx,  // [N_CLASS, N_MU]
    float*       __restrict__ ws_sc,   // [N_CLASS, N_MU]
    int*         __restrict__ flags)   // [N_CLASS]
{
    __shared__ u64 keys[SORTN];
    __shared__ int listed;
    const int e = blockIdx.x;          // class id
    const int t = threadIdx.x;

    if (t == 0) listed = 0;
    __syncthreads();
    for (int i = t; i < n_idx; i += 1024)
        if (cls_idx[i] == e) listed = 1;   // benign race, same value
    __syncthreads();
    if (t == 0) flags[e] = listed;
    if (!listed) return;

    const int c = e;
    const int lane = t & 63;
    const int w    = t >> 6;
    const int i0   = (w << 7) | (lane << 1);   // my slot-0 element index
    const int i1   = i0 | 1;

    auto make_key = [&](int i) -> u64 {
        if (i >= NCAND) return 0xFFFFFFFFFFFFFFFFull;
        float f = (i < N_MU) ? q_sc[(size_t)c * N_MU + i]
                             : inp_sc[(size_t)(i - N_MU) * N_CLASS + c];
        unsigned u = __float_as_uint(f);
        unsigned s = (u & 0x80000000u) ? ~u : (u | 0x80000000u);
        return ((u64)(~s) << 32) | (unsigned)i;
    };
    u64 e0 = make_key(i0);
    u64 e1 = make_key(i1);

    for (int k = 2; k <= SORTN; k <<= 1) {
        // --- cross-wave stages (j >= 128) through LDS ---
        if (k >= 256) {
            keys[i0] = e0; keys[i1] = e1;
            __syncthreads();
            for (int j = k >> 1; j >= 128; j >>= 1) {
                const int i = ((t & ~(j - 1)) << 1) | (t & (j - 1));
                const int p = i | j;
                const bool asc = ((i & k) == 0);
                u64 a = keys[i], b = keys[p];
                const bool sw = asc ? (a > b) : (a < b);
                if (sw) { keys[i] = b; keys[p] = a; }
                __syncthreads();
            }
            e0 = keys[i0]; e1 = keys[i1];
        }
        // --- intra-wave stages j = min(k/2,64) .. 2 via shfl_xor ---
        const bool asc = ((i0 & k) == 0);      // same for both slots (k >= 2)
        for (int j = (k >> 1) < 64 ? (k >> 1) : 64; j >= 2; j >>= 1) {
            const u64 o0 = __shfl_xor(e0, j >> 1);
            const u64 o1 = __shfl_xor(e1, j >> 1);
            const bool low = ((i0 & j) == 0);  // same for both slots (j >= 2)
            const bool takeMin = (low == asc);
            e0 = takeMin ? (e0 < o0 ? e0 : o0) : (e0 > o0 ? e0 : o0);
            e1 = takeMin ? (e1 < o1 ? e1 : o1) : (e1 > o1 ? e1 : o1);
        }
        // --- j == 1 in-thread ---
        {
            const u64 lo = e0 < e1 ? e0 : e1;
            const u64 hi = e0 < e1 ? e1 : e0;
            e0 = asc ? lo : hi;
            e1 = asc ? hi : lo;
        }
    }

    // elements 0..1023 (waves 0..7) are the stable top-1024
    if (w < 8) {
        auto emit = [&](u64 key, int slot) {
            const int idx = (int)(key & 0xFFFFFFFFu);
            unsigned s = ~((unsigned)(key >> 32));
            unsigned u = (s & 0x80000000u) ? (s & 0x7FFFFFFFu) : ~s;
            ws_idx[((size_t)c << 10) + slot] = idx;
            ws_sc [((size_t)c << 10) + slot] = __uint_as_float(u);
        };
        emit(e0, i0);
        emit(e1, i1);
    }
}

// ---------------------------------------------------------------------------
// Kernel 2 (fused gather+fill, software-pipelined): one 512-thread block per
// (class, 16-row group). Per-lane ws_idx loads broadcast from L1. Two-half
// pipeline: stage rows 0-7 | issue 8-15 loads then store 0-7 | store 8-15.
// All global traffic f4; NT on read-once q_mu and all out stores; plain
// loads keep 1 MB inp_mu L2-resident.
// ---------------------------------------------------------------------------
__global__ __launch_bounds__(TPB) void out_kernel(
    const float* __restrict__ q_mu,   // [N_CLASS, N_MU, DIM]
    const float* __restrict__ q_sc,   // [N_CLASS, N_MU]
    const float* __restrict__ inp_mu, // [KIN, DIM]
    const int*   __restrict__ ws_idx, // [N_CLASS, N_MU]
    const float* __restrict__ ws_sc,  // [N_CLASS, N_MU]
    const int*   __restrict__ flags,  // [N_CLASS]
    float*       __restrict__ out)    // [N_CLASS, N_MU, DIM+1]
{
    __shared__ __align__(16) float buf[RPB * (DIM + 1)]; // 8208 floats
    const int b  = blockIdx.x;
    const int c  = b >> 6;          // 64 groups per class
    const int g  = b & 63;
    const int j0 = g * RPB;
    const int t  = threadIdx.x;
    const size_t rowbase = ((size_t)c << 10) + j0;
    const bool upd = (flags[c] != 0);

    auto load_f4 = [&](int r, int q) -> f4 {
        if (upd) {
            const int idx = ws_idx[rowbase + r];
            if (idx < N_MU) {
                return __builtin_nontemporal_load(
                    (const f4*)(q_mu + (((size_t)c << 10) + idx) * DIM) + q);
            }
            return *((const f4*)(inp_mu + (size_t)(idx - N_MU) * DIM) + q);
        }
        return __builtin_nontemporal_load(
            (const f4*)(q_mu + (rowbase + r) * DIM) + q);
    };
    auto load_sc = [&](int r) -> float {
        return upd ? ws_sc[rowbase + r] : q_sc[rowbase + r];
    };
    f4* dst = (f4*)(out + rowbase * (size_t)(DIM + 1));

    // ---- phase A: stage rows 0-7 ----
    {
        f4 v[2];
#pragma unroll
        for (int j = 0; j < 2; ++j) {
            const int fq = t + TPB * j;       // 0..1023
            v[j] = load_f4(fq >> 7, fq & 127);
        }
        float s = (t < 8) ? load_sc(t) : 0.0f;
#pragma unroll
        for (int j = 0; j < 2; ++j) {
            const int fq = t + TPB * j;
            const int r = fq >> 7, q = fq & 127;
            float* d = buf + r * (DIM + 1) + q * 4;
            d[0] = v[j].x; d[1] = v[j].y; d[2] = v[j].z; d[3] = v[j].w;
        }
        if (t < 8) buf[t * (DIM + 1) + DIM] = s;
    }
    __syncthreads();

    // ---- phase B: issue rows 8-15 loads, store rows 0-7, write rows 8-15 ----
    {
        f4 v[2];
#pragma unroll
        for (int j = 0; j < 2; ++j) {
            const int fq = 1024 + t + TPB * j;  // 1024..2047
            v[j] = load_f4(fq >> 7, fq & 127);
        }
        float s = (t < 8) ? load_sc(8 + t) : 0.0f;

        // store region A: f4 slots [0, 1026) — floats [0, 4104) = rows 0-7
        __builtin_nontemporal_store(*(const f4*)(buf + t * 4),            dst + t);
        __builtin_nontemporal_store(*(const f4*)(buf + (TPB + t) * 4),    dst + TPB + t);
        if (t < 2)
            __builtin_nontemporal_store(*(const f4*)(buf + (1024 + t) * 4), dst + 1024 + t);

#pragma unroll
        for (int j = 0; j < 2; ++j) {
            const int fq = 1024 + t + TPB * j;
            const int r = fq >> 7, q = fq & 127;
            float* d = buf + r * (DIM + 1) + q * 4;
            d[0] = v[j].x; d[1] = v[j].y; d[2] = v[j].z; d[3] = v[j].w;
        }
        if (t < 8) buf[(8 + t) * (DIM + 1) + DIM] = s;
    }
    __syncthreads();

    // ---- phase C: store region B: f4 slots [1026, 2052) ----
    __builtin_nontemporal_store(*(const f4*)(buf + (1026 + t) * 4),       dst + 1026 + t);
    __builtin_nontemporal_store(*(const f4*)(buf + (1538 + t) * 4),       dst + 1538 + t);
    if (t < 2)
        __builtin_nontemporal_store(*(const f4*)(buf + (2050 + t) * 4),   dst + 2050 + t);
}

extern "C" void kernel_launch(void* const* d_in, const int* in_sizes, int n_in,
                              void* d_out, int out_size, void* d_ws, size_t ws_size,
                              hipStream_t stream) {
    const float* q_mu    = (const float*)d_in[0];
    const float* q_sc    = (const float*)d_in[1];
    const float* inp_mu  = (const float*)d_in[2];
    const float* inp_sc  = (const float*)d_in[3];
    const int*   cls_idx = (const int*)d_in[4];
    float* out = (float*)d_out;
    const int n_idx = in_sizes[4];

    // workspace: ws_idx [200*1024 int] | ws_sc [200*1024 f32] | flags [200 int]
    constexpr size_t NQ = (size_t)N_CLASS * N_MU;
    int*   ws_idx = (int*)d_ws;
    float* ws_sc  = (float*)((char*)d_ws + NQ * 4);
    int*   flags  = (int*)((char*)d_ws + NQ * 8);

    sort_kernel<<<N_CLASS, 1024, 0, stream>>>(
        q_sc, inp_sc, cls_idx, n_idx, ws_idx, ws_sc, flags);
    out_kernel<<<N_CLASS * (N_MU / RPB), TPB, 0, stream>>>(
        q_mu, q_sc, inp_mu, ws_idx, ws_sc, flags, out);
}